// Round 7
// baseline (100.258 us; speedup 1.0000x reference)
//
#include <hip/hip_runtime.h>
#include <hip/hip_bf16.h>
#include <math.h>

#define BB 4
#define NN 512
#define DD 256
#define LL 64

#define K1_NR 4   // x rows per block in projection kernel
#define IPB  4    // i-rows per block in main kernel (512 blocks = 2/CU)
#define WSTRIDE 132  // 128 cols + 4 pad; b128 bank map == contiguous (4l mod 32)

// ---------------------------------------------------------------------------
// ATTRIBUTION ROUND: kernels byte-identical to round 5 (best: 77.6 us).
// k1 launched x3, k2 launched x2 (both idempotent). With round-5's
// M5 = F + k1 + k2 = 77.6 and this round's M = F + 3*k1 + 2*k2,
// solve for k1, k2 individually. No kernel edits.
// ---------------------------------------------------------------------------
__global__ __launch_bounds__(256) void k1_proj(const float* __restrict__ x,
                                               const float* __restrict__ Wp,
                                               float* __restrict__ xhatT) {
  __shared__ __align__(16) float Wl[LL * WSTRIDE]; // 33,792 B
  __shared__ __align__(16) float xs[K1_NR * DD];   //  4,096 B
  const int bx = blockIdx.x;
  const int b  = bx / (NN / K1_NR);
  const int n0 = (bx % (NN / K1_NR)) * K1_NR;
  const int t  = threadIdx.x;
  const int l  = t & 63;
  const int r  = t >> 6;

  #pragma unroll
  for (int k = 0; k < K1_NR; ++k)
    xs[k * DD + t] = x[((size_t)(b * NN + n0 + k)) * DD + t];

  float4 acc4 = make_float4(0.f, 0.f, 0.f, 0.f);
  #pragma unroll
  for (int h = 0; h < 2; ++h) {
    __syncthreads();                  // protects xs (h=0) / Wl reuse (h=1)
    #pragma unroll
    for (int kk = 0; kk < 32; ++kk) {
      int idx = kk * 256 + t;
      int ll  = idx >> 7;
      int dd  = idx & 127;
      Wl[ll * WSTRIDE + dd] = Wp[ll * DD + h * 128 + dd];
    }
    __syncthreads();
    const float4* xrow = (const float4*)&xs[r * DD + h * 128]; // wave-uniform
    const float4* wrow = (const float4*)&Wl[l * WSTRIDE];
    #pragma unroll 4
    for (int dd = 0; dd < 32; ++dd) {
      float4 xv = xrow[dd];
      float4 wv = wrow[dd];
      acc4.x += xv.x * wv.x;
      acc4.y += xv.y * wv.y;
      acc4.z += xv.z * wv.z;
      acc4.w += xv.w * wv.w;
    }
  }
  float acc = (acc4.x + acc4.y) + (acc4.z + acc4.w);
  xhatT[(size_t)b * (LL * NN) + (size_t)l * NN + (n0 + r)] = acc;
}

__global__ __launch_bounds__(512) void k2_main(const float* __restrict__ xhatT,
                                               const float* __restrict__ adj,
                                               const float* __restrict__ lw,
                                               float* __restrict__ out) {
  __shared__ __align__(16) float xi_s[LL * IPB];  // [l][r], pre-scaled by w
  __shared__ float w_s[LL];
  __shared__ float redm[IPB * 8];
  __shared__ float reds[IPB * 8];

  const int bx   = blockIdx.x;
  const int b    = bx / (NN / IPB);
  const int i0   = (bx % (NN / IPB)) * IPB;
  const int t    = threadIdx.x;      // j
  const int wave = t >> 6;
  const int lane = t & 63;

  const float* xb = xhatT + (size_t)b * (LL * NN);

  if (t < LL * IPB) {                // 256 threads stage the xi tile
    int l = t >> 2, r = t & 3;
    xi_s[t] = lw[l] * xb[l * NN + i0 + r];
  }
  if (t < LL) w_s[t] = lw[t];
  __syncthreads();

  float acc[IPB];
  #pragma unroll
  for (int r = 0; r < IPB; ++r) acc[r] = 0.f;

  const float4* xi4 = (const float4*)xi_s;
  #pragma unroll 4
  for (int l = 0; l < LL; ++l) {
    float pj = w_s[l] * xb[l * NN + t];   // coalesced, L2-resident
    float4 a = xi4[l];                    // broadcast b128
    acc[0] += fabsf(a.x - pj);
    acc[1] += fabsf(a.y - pj);
    acc[2] += fabsf(a.z - pj);
    acc[3] += fabsf(a.w - pj);
  }

  // leaky_relu (dist >= 0 in practice, but stay faithful)
  #pragma unroll
  for (int r = 0; r < IPB; ++r) {
    float d = acc[r];
    acc[r] = d >= 0.f ? d : 0.01f * d;
  }

  // row max over 512 j: wave shfl reduce, then cross-wave via LDS
  #pragma unroll
  for (int r = 0; r < IPB; ++r) {
    float m = acc[r];
    #pragma unroll
    for (int off = 32; off > 0; off >>= 1)
      m = fmaxf(m, __shfl_xor(m, off, 64));
    if (lane == 0) redm[r * 8 + wave] = m;
  }
  __syncthreads();

  float e[IPB];
  const float* adjb = adj + ((size_t)b * NN + i0) * NN;
  #pragma unroll
  for (int r = 0; r < IPB; ++r) {
    float m = redm[r * 8 + 0];
    #pragma unroll
    for (int k = 1; k < 8; ++k) m = fmaxf(m, redm[r * 8 + k]);  // broadcast reads
    e[r] = adjb[(size_t)r * NN + t] * __expf(acc[r] - m);
  }

  // row sum
  #pragma unroll
  for (int r = 0; r < IPB; ++r) {
    float s = e[r];
    #pragma unroll
    for (int off = 32; off > 0; off >>= 1)
      s += __shfl_xor(s, off, 64);
    if (lane == 0) reds[r * 8 + wave] = s;
  }
  __syncthreads();

  float* outb = out + ((size_t)b * NN + i0) * NN;
  #pragma unroll
  for (int r = 0; r < IPB; ++r) {
    float s = reds[r * 8 + 0];
    #pragma unroll
    for (int k = 1; k < 8; ++k) s += reds[r * 8 + k];
    outb[(size_t)r * NN + t] = e[r] / s + 1e-10f;   // epsilon AFTER division
  }
}

extern "C" void kernel_launch(void* const* d_in, const int* in_sizes, int n_in,
                              void* d_out, int out_size, void* d_ws, size_t ws_size,
                              hipStream_t stream) {
  const float* x   = (const float*)d_in[0];   // [B,N,D]
  const float* adj = (const float*)d_in[1];   // [B,N,N]
  const float* Wp  = (const float*)d_in[2];   // [L,D]
  const float* lw  = (const float*)d_in[3];   // [L]
  float* out   = (float*)d_out;               // [B,N,N]
  float* xhatT = (float*)d_ws;                // B*L*N floats = 512 KiB

  // k1 x3, k2 x2 — timing attribution (idempotent; same work every call).
  hipLaunchKernelGGL(k1_proj, dim3(BB * NN / K1_NR), dim3(256), 0, stream,
                     x, Wp, xhatT);
  hipLaunchKernelGGL(k1_proj, dim3(BB * NN / K1_NR), dim3(256), 0, stream,
                     x, Wp, xhatT);
  hipLaunchKernelGGL(k1_proj, dim3(BB * NN / K1_NR), dim3(256), 0, stream,
                     x, Wp, xhatT);
  hipLaunchKernelGGL(k2_main, dim3(BB * NN / IPB), dim3(512), 0, stream,
                     xhatT, adj, lw, out);
  hipLaunchKernelGGL(k2_main, dim3(BB * NN / IPB), dim3(512), 0, stream,
                     xhatT, adj, lw, out);
}

// Round 8
// 89.977 us; speedup vs baseline: 1.1143x; 1.1143x over previous
//
#include <hip/hip_runtime.h>
#include <hip/hip_bf16.h>
#include <math.h>

#define BB 4
#define NN 512
#define DD 256
#define LL 64

#define K1_NR 4   // x rows per block in projection kernel
#define IPB  4    // i-rows per block in main kernel (512 blocks = 2/CU)
#define WSTRIDE 132  // 128 cols + 4 pad for k1's float4 LDS reads

// ---------------------------------------------------------------------------
// k1: x_hatT[b][l][n] = sum_d x[b][n][d] * W[l][d]
// UNCHANGED (attribution: k1 ~ 2-6 us, not the bottleneck).
// ---------------------------------------------------------------------------
__global__ __launch_bounds__(256) void k1_proj(const float* __restrict__ x,
                                               const float* __restrict__ Wp,
                                               float* __restrict__ xhatT) {
  __shared__ __align__(16) float Wl[LL * WSTRIDE]; // 33,792 B
  __shared__ __align__(16) float xs[K1_NR * DD];   //  4,096 B
  const int bx = blockIdx.x;
  const int b  = bx / (NN / K1_NR);
  const int n0 = (bx % (NN / K1_NR)) * K1_NR;
  const int t  = threadIdx.x;
  const int l  = t & 63;
  const int r  = t >> 6;

  #pragma unroll
  for (int k = 0; k < K1_NR; ++k)
    xs[k * DD + t] = x[((size_t)(b * NN + n0 + k)) * DD + t];

  float4 acc4 = make_float4(0.f, 0.f, 0.f, 0.f);
  #pragma unroll
  for (int h = 0; h < 2; ++h) {
    __syncthreads();                  // protects xs (h=0) / Wl reuse (h=1)
    #pragma unroll
    for (int kk = 0; kk < 32; ++kk) {
      int idx = kk * 256 + t;
      int ll  = idx >> 7;
      int dd  = idx & 127;
      Wl[ll * WSTRIDE + dd] = Wp[ll * DD + h * 128 + dd];
    }
    __syncthreads();
    const float4* xrow = (const float4*)&xs[r * DD + h * 128]; // wave-uniform
    const float4* wrow = (const float4*)&Wl[l * WSTRIDE];
    #pragma unroll 4
    for (int dd = 0; dd < 32; ++dd) {
      float4 xv = xrow[dd];
      float4 wv = wrow[dd];
      acc4.x += xv.x * wv.x;
      acc4.y += xv.y * wv.y;
      acc4.z += xv.z * wv.z;
      acc4.w += xv.w * wv.w;
    }
  }
  float acc = (acc4.x + acc4.y) + (acc4.z + acc4.w);
  xhatT[(size_t)b * (LL * NN) + (size_t)l * NN + (n0 + r)] = acc;
}

// ---------------------------------------------------------------------------
// k2 THIS ROUND: latency-source removal.
//  * xi/w are block-uniform -> loaded via uniform addresses so the backend
//    scalarizes them to s_load_dwordx4 / s_load_dword (SMEM pipe, hoisted;
//    zero LDS, zero per-lane VMEM in the inner loop).
//  * pj[64] hoisted to VGPRs: 64 coalesced loads issued back-to-back, one
//    drain. Live set ~90 VGPR < 128 (__launch_bounds__(512,4) pins the cap;
//    round 6's regression had LDS float4 + staging on top -> spill).
//  * w >= 0 identity used as w * |xi - pj| (v_sub + v_fma with abs modifier).
// ---------------------------------------------------------------------------
__global__ __launch_bounds__(512, 4) void k2_main(const float* __restrict__ xhatT,
                                                  const float* __restrict__ adj,
                                                  const float* __restrict__ lw,
                                                  float* __restrict__ out) {
  __shared__ float redm[IPB * 8];
  __shared__ float reds[IPB * 8];

  const int bx   = blockIdx.x;
  const int b    = bx / (NN / IPB);
  const int i0   = (bx % (NN / IPB)) * IPB;
  const int t    = threadIdx.x;      // j
  const int wave = t >> 6;
  const int lane = t & 63;

  const float* xb = xhatT + (size_t)b * (LL * NN);

  // per-thread column of x_hat^T: 64 coalesced loads, all in flight at once
  float pj[LL];
  #pragma unroll
  for (int l = 0; l < LL; ++l)
    pj[l] = xb[l * NN + t];

  float acc[IPB];
  #pragma unroll
  for (int r = 0; r < IPB; ++r) acc[r] = 0.f;

  #pragma unroll
  for (int l = 0; l < LL; ++l) {
    const float  w  = lw[l];                                        // uniform -> s_load
    const float4 xi = *(const float4*)(xb + (size_t)l * NN + i0);   // uniform -> s_load_dwordx4
    const float  p  = pj[l];
    acc[0] += w * fabsf(xi.x - p);
    acc[1] += w * fabsf(xi.y - p);
    acc[2] += w * fabsf(xi.z - p);
    acc[3] += w * fabsf(xi.w - p);
  }

  // leaky_relu (dist >= 0 in practice, but stay faithful)
  #pragma unroll
  for (int r = 0; r < IPB; ++r) {
    float d = acc[r];
    acc[r] = d >= 0.f ? d : 0.01f * d;
  }

  // row max over 512 j: wave shfl reduce, then cross-wave via LDS
  #pragma unroll
  for (int r = 0; r < IPB; ++r) {
    float m = acc[r];
    #pragma unroll
    for (int off = 32; off > 0; off >>= 1)
      m = fmaxf(m, __shfl_xor(m, off, 64));
    if (lane == 0) redm[r * 8 + wave] = m;
  }
  __syncthreads();

  float e[IPB];
  const float* adjb = adj + ((size_t)b * NN + i0) * NN;
  #pragma unroll
  for (int r = 0; r < IPB; ++r) {
    float m = redm[r * 8 + 0];
    #pragma unroll
    for (int k = 1; k < 8; ++k) m = fmaxf(m, redm[r * 8 + k]);  // broadcast reads
    e[r] = adjb[(size_t)r * NN + t] * __expf(acc[r] - m);
  }

  // row sum
  #pragma unroll
  for (int r = 0; r < IPB; ++r) {
    float s = e[r];
    #pragma unroll
    for (int off = 32; off > 0; off >>= 1)
      s += __shfl_xor(s, off, 64);
    if (lane == 0) reds[r * 8 + wave] = s;
  }
  __syncthreads();

  float* outb = out + ((size_t)b * NN + i0) * NN;
  #pragma unroll
  for (int r = 0; r < IPB; ++r) {
    float s = reds[r * 8 + 0];
    #pragma unroll
    for (int k = 1; k < 8; ++k) s += reds[r * 8 + k];
    outb[(size_t)r * NN + t] = e[r] / s + 1e-10f;   // epsilon AFTER division
  }
}

extern "C" void kernel_launch(void* const* d_in, const int* in_sizes, int n_in,
                              void* d_out, int out_size, void* d_ws, size_t ws_size,
                              hipStream_t stream) {
  const float* x   = (const float*)d_in[0];   // [B,N,D]
  const float* adj = (const float*)d_in[1];   // [B,N,N]
  const float* Wp  = (const float*)d_in[2];   // [L,D]
  const float* lw  = (const float*)d_in[3];   // [L]
  float* out   = (float*)d_out;               // [B,N,N]
  float* xhatT = (float*)d_ws;                // B*L*N floats = 512 KiB

  hipLaunchKernelGGL(k1_proj, dim3(BB * NN / K1_NR), dim3(256), 0, stream,
                     x, Wp, xhatT);
  hipLaunchKernelGGL(k2_main, dim3(BB * NN / IPB), dim3(512), 0, stream,
                     xhatT, adj, lw, out);
}

// Round 9
// 79.200 us; speedup vs baseline: 1.2659x; 1.1361x over previous
//
#include <hip/hip_runtime.h>
#include <hip/hip_bf16.h>
#include <math.h>

#define BB 4
#define NN 512
#define DD 256
#define LL 64

#define K1_NR 4      // x rows per block in projection kernel
#define IPB  4       // i-rows per block in main kernel (512 blocks = 2/CU)
#define WSTRIDE 132  // 128 cols + 4 pad for k1's float4 LDS reads
#define LCHUNK 16    // l-rows staged per phase in k2 (32 KB LDS)

// ---------------------------------------------------------------------------
// k1: x_hatT[b][l][n] = sum_d x[b][n][d] * W[l][d]
// UNCHANGED (attribution: k1 ~ 2-5 us, not the bottleneck).
// ---------------------------------------------------------------------------
__global__ __launch_bounds__(256) void k1_proj(const float* __restrict__ x,
                                               const float* __restrict__ Wp,
                                               float* __restrict__ xhatT) {
  __shared__ __align__(16) float Wl[LL * WSTRIDE]; // 33,792 B
  __shared__ __align__(16) float xs[K1_NR * DD];   //  4,096 B
  const int bx = blockIdx.x;
  const int b  = bx / (NN / K1_NR);
  const int n0 = (bx % (NN / K1_NR)) * K1_NR;
  const int t  = threadIdx.x;
  const int l  = t & 63;
  const int r  = t >> 6;

  #pragma unroll
  for (int k = 0; k < K1_NR; ++k)
    xs[k * DD + t] = x[((size_t)(b * NN + n0 + k)) * DD + t];

  float4 acc4 = make_float4(0.f, 0.f, 0.f, 0.f);
  #pragma unroll
  for (int h = 0; h < 2; ++h) {
    __syncthreads();                  // protects xs (h=0) / Wl reuse (h=1)
    #pragma unroll
    for (int kk = 0; kk < 32; ++kk) {
      int idx = kk * 256 + t;
      int ll  = idx >> 7;
      int dd  = idx & 127;
      Wl[ll * WSTRIDE + dd] = Wp[ll * DD + h * 128 + dd];
    }
    __syncthreads();
    const float4* xrow = (const float4*)&xs[r * DD + h * 128]; // wave-uniform
    const float4* wrow = (const float4*)&Wl[l * WSTRIDE];
    #pragma unroll 4
    for (int dd = 0; dd < 32; ++dd) {
      float4 xv = xrow[dd];
      float4 wv = wrow[dd];
      acc4.x += xv.x * wv.x;
      acc4.y += xv.y * wv.y;
      acc4.z += xv.z * wv.z;
      acc4.w += xv.w * wv.w;
    }
  }
  float acc = (acc4.x + acc4.y) + (acc4.z + acc4.w);
  xhatT[(size_t)b * (LL * NN) + (size_t)l * NN + (n0 + r)] = acc;
}

// ---------------------------------------------------------------------------
// k2 THIS ROUND: bulk-staged phases instead of per-iteration L2 loads.
// 4 phases; each stages 16 l-rows x 512 j of x_hat^T (32 KB) into LDS with
// dense coalesced float4 loads (pre-scaled by w at staging; w>=0 identity),
// then computes purely from LDS+VALU. Inner loop: 1 ds_read_b32 (pj, lane-
// consecutive = conflict-free) + 1 ds_read_b128 (xi broadcast) + 8 VALU.
// Rounds 6/8 lesson: NO full-array register hoists; rolling bounded unroll.
// ---------------------------------------------------------------------------
__global__ __launch_bounds__(512) void k2_main(const float* __restrict__ xhatT,
                                               const float* __restrict__ adj,
                                               const float* __restrict__ lw,
                                               float* __restrict__ out) {
  __shared__ __align__(16) float pj_s[LCHUNK * NN];  // 32 KB, pre-scaled by w
  __shared__ __align__(16) float xi_s[LL * IPB];     // [l][r], pre-scaled by w
  __shared__ float w_s[LL];
  __shared__ float redm[IPB * 8];
  __shared__ float reds[IPB * 8];

  const int bx   = blockIdx.x;
  const int b    = bx / (NN / IPB);
  const int i0   = (bx % (NN / IPB)) * IPB;
  const int t    = threadIdx.x;      // j
  const int wave = t >> 6;
  const int lane = t & 63;

  const float* xb = xhatT + (size_t)b * (LL * NN);

  if (t < LL * IPB) {                // 256 threads stage the xi tile
    int l = t >> 2, r = t & 3;
    xi_s[t] = lw[l] * xb[l * NN + i0 + r];
  }
  if (t < LL) w_s[t] = lw[t];

  float acc[IPB];
  #pragma unroll
  for (int r = 0; r < IPB; ++r) acc[r] = 0.f;

  const float4* xi4 = (const float4*)xi_s;

  for (int lc = 0; lc < LL / LCHUNK; ++lc) {
    __syncthreads();   // lc=0: xi_s/w_s ready; lc>0: prev chunk fully consumed
    // stage chunk: LCHUNK*NN = 8192 floats = 2048 float4 = 512 thr x 4
    {
      const float4* src = (const float4*)(xb + (size_t)lc * LCHUNK * NN);
      float4* dst = (float4*)pj_s;
      #pragma unroll
      for (int k = 0; k < 4; ++k) {
        int e  = k * 512 + t;        // float4 index within chunk
        int li = e >> 7;             // 128 float4 per l-row
        float w = w_s[lc * LCHUNK + li];
        float4 v = src[e];
        v.x *= w; v.y *= w; v.z *= w; v.w *= w;
        dst[e] = v;
      }
    }
    __syncthreads();
    #pragma unroll 4
    for (int li = 0; li < LCHUNK; ++li) {
      int l = lc * LCHUNK + li;
      float  p = pj_s[li * NN + t];  // b32, lane-consecutive, conflict-free
      float4 a = xi4[l];             // broadcast ds_read_b128
      acc[0] += fabsf(a.x - p);
      acc[1] += fabsf(a.y - p);
      acc[2] += fabsf(a.z - p);
      acc[3] += fabsf(a.w - p);
    }
  }

  // leaky_relu (dist >= 0 in practice, but stay faithful)
  #pragma unroll
  for (int r = 0; r < IPB; ++r) {
    float d = acc[r];
    acc[r] = d >= 0.f ? d : 0.01f * d;
  }

  // row max over 512 j: wave shfl reduce, then cross-wave via LDS
  #pragma unroll
  for (int r = 0; r < IPB; ++r) {
    float m = acc[r];
    #pragma unroll
    for (int off = 32; off > 0; off >>= 1)
      m = fmaxf(m, __shfl_xor(m, off, 64));
    if (lane == 0) redm[r * 8 + wave] = m;
  }
  __syncthreads();

  float e[IPB];
  const float* adjb = adj + ((size_t)b * NN + i0) * NN;
  #pragma unroll
  for (int r = 0; r < IPB; ++r) {
    float m = redm[r * 8 + 0];
    #pragma unroll
    for (int k = 1; k < 8; ++k) m = fmaxf(m, redm[r * 8 + k]);  // broadcast reads
    e[r] = adjb[(size_t)r * NN + t] * __expf(acc[r] - m);
  }

  // row sum
  #pragma unroll
  for (int r = 0; r < IPB; ++r) {
    float s = e[r];
    #pragma unroll
    for (int off = 32; off > 0; off >>= 1)
      s += __shfl_xor(s, off, 64);
    if (lane == 0) reds[r * 8 + wave] = s;
  }
  __syncthreads();

  float* outb = out + ((size_t)b * NN + i0) * NN;
  #pragma unroll
  for (int r = 0; r < IPB; ++r) {
    float s = reds[r * 8 + 0];
    #pragma unroll
    for (int k = 1; k < 8; ++k) s += reds[r * 8 + k];
    outb[(size_t)r * NN + t] = e[r] / s + 1e-10f;   // epsilon AFTER division
  }
}

extern "C" void kernel_launch(void* const* d_in, const int* in_sizes, int n_in,
                              void* d_out, int out_size, void* d_ws, size_t ws_size,
                              hipStream_t stream) {
  const float* x   = (const float*)d_in[0];   // [B,N,D]
  const float* adj = (const float*)d_in[1];   // [B,N,N]
  const float* Wp  = (const float*)d_in[2];   // [L,D]
  const float* lw  = (const float*)d_in[3];   // [L]
  float* out   = (float*)d_out;               // [B,N,N]
  float* xhatT = (float*)d_ws;                // B*L*N floats = 512 KiB

  hipLaunchKernelGGL(k1_proj, dim3(BB * NN / K1_NR), dim3(256), 0, stream,
                     x, Wp, xhatT);
  hipLaunchKernelGGL(k2_main, dim3(BB * NN / IPB), dim3(512), 0, stream,
                     xhatT, adj, lw, out);
}